// Round 21
// baseline (162.156 us; speedup 1.0000x reference)
//
#include <hip/hip_runtime.h>
#include <math.h>

typedef unsigned short u16;
typedef unsigned int u32;

#define INV_LN2 1.44269504088896f
#define LN2     0.693147180559945f
#define NEG2    (-14426.9504f)          // -10000 * INV_LN2

// Problem dims (fixed): B=64, T_seq=256, T_mel=2048, D=80; SSIM out = 2038 x 70

#define NPART 16                 // minmax parts per batch (128 rows each)

struct Ws {
  double ssim_sum;
  double dur_sum;
  double spec_part[64 * NPART];
  float  mnT[64 * NPART], mxT[64 * NPART], mnO[64 * NPART], mxO[64 * NPART];
  float  A[64 * 256];    // fwd alpha at t=1023 (log2 domain)
  float  Bv[64 * 256];   // bwd beta  at t=1023 (log2 domain)
  float  ckF[64 * 256];  // fwd checkpoint after t=511
  float  ckB[64 * 256];  // bwd checkpoint after tiles kbT..kbT-15
};

__device__ __forceinline__ float lse2f(float a, float b) {
  float m = fmaxf(a, b);
  float d = fabsf(a - b);
  return m + __builtin_amdgcn_logf(1.0f + __builtin_amdgcn_exp2f(-d));
}
__device__ __forceinline__ float lae2g(float a, float b, float g) {
  float m = fmaxf(a, b);
  float d = fabsf(a - b);
  return (m + g) + __builtin_amdgcn_logf(1.0f + __builtin_amdgcn_exp2f(-d));
}
__device__ __forceinline__ u16 bf16rn(float f) {
  u32 u = __float_as_uint(f);
  u32 r = (u + 0x7fffu + ((u >> 16) & 1u)) >> 16;
  return (u16)r;
}

constexpr float G11[11] = {
  0.00102838f, 0.00759876f, 0.03600077f, 0.10936070f, 0.21300554f,
  0.26601172f,
  0.21300554f, 0.10936070f, 0.03600077f, 0.00759876f, 0.00102838f};

#define TSTR 264                 // u16 row stride per t_local
#define TSZ  (32 * TSTR)

// Producers (lanes 64..255): stage tile kb (32 t-steps), transposed
// [t][s] bf16, pre-scaled by 1/ln2.  Identical to round-12 (verified).
__device__ __forceinline__ void stage_tile(const float* __restrict__ gb, int kb,
                                           u16* dst, int tid) {
  const int ltid = tid - 64;
  const int tb = kb << 5;
#pragma unroll
  for (int it = 0; it < 11; ++it) {
    int i = ltid + it * 192;
    if (i < 2048) {
      int s = i >> 3, e = i & 7;
      float4 v = *(const float4*)(gb + (size_t)s * 2048 + tb + 4 * e);
      u16* d = dst + (4 * e) * TSTR + s;
      d[0]        = bf16rn(v.x * INV_LN2);
      d[TSTR]     = bf16rn(v.y * INV_LN2);
      d[2 * TSTR] = bf16rn(v.z * INV_LN2);
      d[3 * TSTR] = bf16rn(v.w * INV_LN2);
    }
  }
}

// ---------------- Kernel 0: minmax + spec MSE partials || dur ----------------
__global__ __launch_bounds__(256) void k0(
    const float* __restrict__ deco, const float* __restrict__ dect,
    const float* __restrict__ duro, const float* __restrict__ durt,
    const int* __restrict__ mel_lens, const int* __restrict__ inp_lens,
    Ws* __restrict__ ws) {
  __shared__ float L[5][4];
  const int bid = blockIdx.x, tid = threadIdx.x;

  if (bid < 64 * NPART) {  // min/max + spec partial: NPART blocks/batch, 128 rows
    int idx = bid, b = idx >> 4, part = idx & (NPART - 1);
    int len = mel_lens[b];
    int rbeg = part * 128;
    int rcnt = len - rbeg; rcnt = rcnt < 0 ? 0 : (rcnt > 128 ? 128 : rcnt);
    float mnT = __builtin_inff(), mxT = -__builtin_inff();
    float mnO = __builtin_inff(), mxO = -__builtin_inff();
    float ssum = 0.f;
    if (rcnt > 0) {
      const float4* po = (const float4*)(deco + ((size_t)(b * 2048 + rbeg)) * 80);
      const float4* pt = (const float4*)(dect + ((size_t)(b * 2048 + rbeg)) * 80);
      int n4 = rcnt * 20;
      for (int i = tid; i < n4; i += 256) {
        float4 vo = po[i], vt = pt[i];
        mnO = fminf(mnO, fminf(fminf(vo.x, vo.y), fminf(vo.z, vo.w)));
        mxO = fmaxf(mxO, fmaxf(fmaxf(vo.x, vo.y), fmaxf(vo.z, vo.w)));
        mnT = fminf(mnT, fminf(fminf(vt.x, vt.y), fminf(vt.z, vt.w)));
        mxT = fmaxf(mxT, fmaxf(fmaxf(vt.x, vt.y), fmaxf(vt.z, vt.w)));
        float dx = vo.x - vt.x, dy = vo.y - vt.y, dz = vo.z - vt.z, dw = vo.w - vt.w;
        ssum += dx * dx + dy * dy + dz * dz + dw * dw;
      }
    }
    for (int o = 32; o; o >>= 1) {
      mnT = fminf(mnT, __shfl_xor(mnT, o));
      mxT = fmaxf(mxT, __shfl_xor(mxT, o));
      mnO = fminf(mnO, __shfl_xor(mnO, o));
      mxO = fmaxf(mxO, __shfl_xor(mxO, o));
      ssum += __shfl_xor(ssum, o);
    }
    int w = tid >> 6;
    if ((tid & 63) == 0) { L[0][w] = mnT; L[1][w] = mxT; L[2][w] = mnO; L[3][w] = mxO; L[4][w] = ssum; }
    __syncthreads();
    if (tid == 0) {
      mnT = fminf(fminf(L[0][0], L[0][1]), fminf(L[0][2], L[0][3]));
      mxT = fmaxf(fmaxf(L[1][0], L[1][1]), fmaxf(L[1][2], L[1][3]));
      mnO = fminf(fminf(L[2][0], L[2][1]), fminf(L[2][2], L[2][3]));
      mxO = fmaxf(fmaxf(L[3][0], L[3][1]), fmaxf(L[3][2], L[3][3]));
      ssum = L[4][0] + L[4][1] + L[4][2] + L[4][3];
      ws->mnT[idx] = mnT; ws->mxT[idx] = mxT; ws->mnO[idx] = mnO; ws->mxO[idx] = mxO;
      ws->spec_part[idx] = (double)ssum;
    }
    return;
  }

  {  // dur MSE + zero ssim accumulator
    float ssum = 0.f;
    for (int i = tid; i < 64 * 256; i += 256) {
      int b2 = i >> 8, s2 = i & 255;
      if (s2 < inp_lens[b2]) { float d = duro[i] - durt[i]; ssum += d * d; }
    }
    for (int o = 32; o; o >>= 1) ssum += __shfl_xor(ssum, o);
    int w = tid >> 6;
    if ((tid & 63) == 0) L[4][w] = ssum;
    __syncthreads();
    if (tid == 0) {
      ws->dur_sum = (double)(L[4][0] + L[4][1] + L[4][2] + L[4][3]);
      ws->ssim_sum = 0.0;
    }
  }
}

// Shared SSIM conv tile body (r18/r20-verified form), 512 threads.
__device__ __forceinline__ void conv_tile(
    int gci, const float* __restrict__ deco, const float* __restrict__ dect,
    const int* __restrict__ mel_lens, Ws* __restrict__ ws, float* SMF, int tid) {
  float* cc = SMF;
  float* R = SMF + 14700;  // [8]
  int b = gci >> 6, tile = gci & 63;
  int r0 = tile * 32;
  int nrows = 2038 - r0; nrows = nrows > 32 ? 32 : nrows;
  int nin = nrows + 10;
  int len = mel_lens[b];

  // EXACT shortcut: tiles fully past the mask -> ssim_map == 1.0 exactly.
  if (r0 >= len) {
    if (tid == 0) atomicAdd(&ws->ssim_sum, (double)(nrows * 70));
    return;
  }

  float mnT = ws->mnT[NPART * b], mxT = ws->mxT[NPART * b];
  float mnO = ws->mnO[NPART * b], mxO = ws->mxO[NPART * b];
#pragma unroll
  for (int p = 1; p < NPART; ++p) {
    mnT = fminf(mnT, ws->mnT[NPART * b + p]);
    mxT = fmaxf(mxT, ws->mxT[NPART * b + p]);
    mnO = fminf(mnO, ws->mnO[NPART * b + p]);
    mxO = fmaxf(mxO, ws->mxO[NPART * b + p]);
  }
  if (len < 2048) { mxT = fmaxf(mxT, 0.f); mxO = fmaxf(mxO, 0.f); }
  float sT = 1.0f / (mxT - mnT + 1e-8f);
  float sO = 1.0f / (mxO - mnO + 1e-8f);
  const float* po = deco + (size_t)b * 2048 * 80;
  const float* pt = dect + (size_t)b * 2048 * 80;

  // Phase A: column conv (80 -> 70), float4-vectorized quad-j tasks.
  for (int task = tid; task < nin * 18; task += 512) {
    int r = task / 18, q = task - 18 * r;
    int j0 = q * 4;
    int grow = r0 + r;
    float sacc[4][5];
#pragma unroll
    for (int e = 0; e < 4; ++e)
#pragma unroll
      for (int c = 0; c < 5; ++c) sacc[e][c] = 0.f;
    if (grow < len) {
      const float* rowt = pt + (size_t)grow * 80 + j0;
      const float* rowo = po + (size_t)grow * 80 + j0;
      float ft[16], fo[16];
      *(float4*)&ft[0]  = *(const float4*)(rowt);
      *(float4*)&ft[4]  = *(const float4*)(rowt + 4);
      *(float4*)&ft[8]  = *(const float4*)(rowt + 8);
      *(float4*)&ft[12] = (j0 == 68) ? *(const float4*)(rowt + 8)
                                     : *(const float4*)(rowt + 12);
      *(float4*)&fo[0]  = *(const float4*)(rowo);
      *(float4*)&fo[4]  = *(const float4*)(rowo + 4);
      *(float4*)&fo[8]  = *(const float4*)(rowo + 8);
      *(float4*)&fo[12] = (j0 == 68) ? *(const float4*)(rowo + 8)
                                     : *(const float4*)(rowo + 12);
#pragma unroll
      for (int i = 0; i < 16; ++i) {
        ft[i] = (ft[i] - mnT) * sT;
        fo[i] = (fo[i] - mnO) * sO;
      }
#pragma unroll
      for (int e = 0; e < 4; ++e) {
#pragma unroll
        for (int k = 0; k < 11; ++k) {
          float tn = ft[e + k], on = fo[e + k], g = G11[k];
          sacc[e][0] = fmaf(g, tn, sacc[e][0]);
          sacc[e][1] = fmaf(g, on, sacc[e][1]);
          sacc[e][2] = fmaf(g * tn, tn, sacc[e][2]);
          sacc[e][3] = fmaf(g * on, on, sacc[e][3]);
          sacc[e][4] = fmaf(g * on, tn, sacc[e][4]);  // g*tn*on (order-equal)
        }
      }
    }
    int base = r * 70 + j0;
#pragma unroll
    for (int c = 0; c < 5; ++c) {
      *(float2*)&cc[c * 2940 + base] = make_float2(sacc[0][c], sacc[1][c]);
      if (j0 < 68)
        *(float2*)&cc[c * 2940 + base + 2] = make_float2(sacc[2][c], sacc[3][c]);
    }
  }
  __syncthreads();

  // Phase B: row conv + SSIM formula (verified simple form)
  float acc = 0.f;
  for (int q2 = tid; q2 < nrows * 70; q2 += 512) {
    int i = q2 / 70, j = q2 - 70 * i;
    float mx = 0, my = 0, xx = 0, yy = 0, xy = 0;
#pragma unroll
    for (int k = 0; k < 11; ++k) {
      float g = G11[k];
      int o = (i + k) * 70 + j;
      mx = fmaf(g, cc[o], mx);
      my = fmaf(g, cc[2940 + o], my);
      xx = fmaf(g, cc[2 * 2940 + o], xx);
      yy = fmaf(g, cc[3 * 2940 + o], yy);
      xy = fmaf(g, cc[4 * 2940 + o], xy);
    }
    float vx = xx - mx * mx, vy = yy - my * my, vxy = xy - mx * my;
    float cs = (2.f * vxy + 9e-4f) / (vx + vy + 9e-4f);
    float lum = (2.f * mx * my + 1e-4f) / (mx * mx + my * my + 1e-4f);
    acc += lum * cs;
  }
  for (int o = 32; o; o >>= 1) acc += __shfl_xor(acc, o);
  if ((tid & 63) == 0) R[tid >> 6] = acc;
  __syncthreads();
  if (tid == 0)
    atomicAdd(&ws->ssim_sum,
              (double)(R[0] + R[1] + R[2] + R[3] + R[4] + R[5] + R[6] + R[7]));
}

// ------- Kernel 1 (512 threads): fwd seg1 || bwd seg1 || conv (even tiles) -------
__global__ __launch_bounds__(512) void kseg1(
    const float* __restrict__ logp,
    const float* __restrict__ deco, const float* __restrict__ dect,
    const int* __restrict__ mel_lens, const int* __restrict__ inp_lens,
    Ws* __restrict__ ws) {
  __shared__ float SMF[14712];   // 58848 B; MDN aliases first 33792 B
  const int bid = blockIdx.x, tid = threadIdx.x;
  const int l = tid;
  u16* TB = (u16*)SMF;

  if (bid < 64) {  // ---- fwd segment 1: tiles 0..15 (t = 1..511) ----
    const int b = bid;
    const float* gb = logp + (size_t)b * 256 * 2048;
    float a0 = NEG2, a1 = NEG2, a2 = NEG2, a3 = NEG2;
    if (tid < 64 && l == 0) a0 = gb[0] * INV_LN2;
    auto FWD = [&](uint2 fg) {
      float g0 = __uint_as_float(fg.x << 16);
      float g1 = __uint_as_float(fg.x & 0xffff0000u);
      float g2 = __uint_as_float(fg.y << 16);
      float g3 = __uint_as_float(fg.y & 0xffff0000u);
      int up = __builtin_amdgcn_update_dpp(
          __float_as_int(NEG2), __float_as_int(a3), 0x138, 0xF, 0xF, false);
      float am1 = __int_as_float(up);
      float n0 = lae2g(a0, am1, g0);
      float n1 = lae2g(a1, a0, g1);
      float n2 = lae2g(a2, a1, g2);
      float n3 = lae2g(a3, a2, g3);
      a0 = n0; a1 = n1; a2 = n2; a3 = n3;
    };
    if (tid >= 64 && tid < 256) stage_tile(gb, 0, TB, tid);
    __syncthreads();
    // j = 0 peel (skip t=0)
    if (tid >= 64 && tid < 256) stage_tile(gb, 1, TB + TSZ, tid);
    else if (tid < 64) {
      const u16* fs = TB + 4 * l;
      for (int i = 1; i < 32; ++i) FWD(*(const uint2*)(fs + i * TSTR));
    }
    __syncthreads();
    for (int j = 1; j < 16; ++j) {
      if (tid >= 64 && tid < 256) {
        if (j < 15) stage_tile(gb, j + 1, TB + ((j + 1) & 1) * TSZ, tid);
      } else if (tid < 64) {
        __builtin_amdgcn_s_setprio(1);
        const u16* fs = TB + (j & 1) * TSZ + 4 * l;
        uint2 fb[2][4];
#pragma unroll
        for (int k = 0; k < 4; ++k) fb[0][k] = *(const uint2*)(fs + k * TSTR);
#pragma unroll
        for (int g = 0; g < 8; ++g) {
          const int cur = g & 1, nxt = cur ^ 1;
          if (g < 7) {
#pragma unroll
            for (int k = 0; k < 4; ++k)
              fb[nxt][k] = *(const uint2*)(fs + ((g + 1) * 4 + k) * TSTR);
          }
#pragma unroll
          for (int k = 0; k < 4; ++k) FWD(fb[cur][k]);
        }
        __builtin_amdgcn_s_setprio(0);
      }
      __syncthreads();
    }
    if (tid < 64)
      *(float4*)&ws->ckF[b * 256 + 4 * l] = make_float4(a0, a1, a2, a3);
    return;
  }

  if (bid < 128) {  // ---- bwd segment 1: tiles kbT..kbT-15 ----
    const int b = bid - 64;
    const int T = mel_lens[b] - 1;
    const int ss = inp_lens[b] - 1;
    const int kbT = T >> 5;
    const float* gb = logp + (size_t)b * 256 * 2048;
    float b0 = NEG2, b1 = NEG2, b2 = NEG2, b3 = NEG2;
    if (tid < 64) {
      b0 = (4 * l + 0 == ss) ? 0.f : NEG2;
      b1 = (4 * l + 1 == ss) ? 0.f : NEG2;
      b2 = (4 * l + 2 == ss) ? 0.f : NEG2;
      b3 = (4 * l + 3 == ss) ? 0.f : NEG2;
    }
    auto BWD = [&](uint2 bg, bool act) {
      float g0 = __uint_as_float(bg.x << 16);
      float g1 = __uint_as_float(bg.x & 0xffff0000u);
      float g2 = __uint_as_float(bg.y << 16);
      float g3 = __uint_as_float(bg.y & 0xffff0000u);
      float c0 = b0 + g0, c1 = b1 + g1, c2 = b2 + g2, c3 = b3 + g3;
      int dn = __builtin_amdgcn_update_dpp(
          __float_as_int(NEG2), __float_as_int(c0), 0x130, 0xF, 0xF, false);
      float cp = __int_as_float(dn);
      float m0 = lse2f(c0, c1);
      float m1 = lse2f(c1, c2);
      float m2 = lse2f(c2, c3);
      float m3 = lse2f(c3, cp);
      b0 = act ? m0 : b0; b1 = act ? m1 : b1;
      b2 = act ? m2 : b2; b3 = act ? m3 : b3;
    };
    if (tid >= 64 && tid < 256) { if (kbT >= 32) stage_tile(gb, kbT, TB, tid); }
    __syncthreads();
    // j = 0 peel (per-t guard tt <= T)
    if (tid >= 64 && tid < 256) {
      if (kbT - 1 >= 32) stage_tile(gb, kbT - 1, TB + TSZ, tid);
    } else if (tid < 64 && kbT >= 32) {
      const u16* bs = TB + 4 * l;
      for (int ii = 31; ii >= 0; --ii) {
        int tt = (kbT << 5) + ii;
        if (tt <= T) BWD(*(const uint2*)(bs + ii * TSTR), true);
      }
    }
    __syncthreads();
    for (int j = 1; j < 16; ++j) {
      if (tid >= 64 && tid < 256) {
        int bk = kbT - j - 1;
        if (j < 15 && bk >= 32) stage_tile(gb, bk, TB + ((j + 1) & 1) * TSZ, tid);
      } else if (tid < 64) {
        __builtin_amdgcn_s_setprio(1);
        const u16* bs = TB + (j & 1) * TSZ + 4 * l;
        const bool act = (kbT - j) >= 32;
        uint2 bb[2][4];
#pragma unroll
        for (int k = 0; k < 4; ++k) bb[0][k] = *(const uint2*)(bs + (31 - k) * TSTR);
#pragma unroll
        for (int g = 0; g < 8; ++g) {
          const int cur = g & 1, nxt = cur ^ 1;
          if (g < 7) {
#pragma unroll
            for (int k = 0; k < 4; ++k)
              bb[nxt][k] = *(const uint2*)(bs + (31 - ((g + 1) * 4 + k)) * TSTR);
          }
#pragma unroll
          for (int k = 0; k < 4; ++k) BWD(bb[cur][k], act);
        }
        __builtin_amdgcn_s_setprio(0);
      }
      __syncthreads();
    }
    if (tid < 64)
      *(float4*)&ws->ckB[b * 256 + 4 * l] = make_float4(b0, b1, b2, b3);
    return;
  }

  // ---- SSIM conv: even global tiles ----
  conv_tile((bid - 128) * 2, deco, dect, mel_lens, ws, SMF, tid);
}

// ------- Kernel 2 (512 threads): fwd seg2 || bwd seg2 || conv (odd tiles) -------
__global__ __launch_bounds__(512) void kseg2(
    const float* __restrict__ logp,
    const float* __restrict__ deco, const float* __restrict__ dect,
    const int* __restrict__ mel_lens, const int* __restrict__ inp_lens,
    Ws* __restrict__ ws) {
  __shared__ float SMF[14712];
  const int bid = blockIdx.x, tid = threadIdx.x;
  const int l = tid;
  u16* TB = (u16*)SMF;

  if (bid < 64) {  // ---- fwd segment 2: tiles 16..31 (t = 512..1023) ----
    const int b = bid;
    const float* gb = logp + (size_t)b * 256 * 2048;
    float a0 = NEG2, a1 = NEG2, a2 = NEG2, a3 = NEG2;
    if (tid < 64) {
      float4 c = *(const float4*)&ws->ckF[b * 256 + 4 * l];
      a0 = c.x; a1 = c.y; a2 = c.z; a3 = c.w;
    }
    auto FWD = [&](uint2 fg) {
      float g0 = __uint_as_float(fg.x << 16);
      float g1 = __uint_as_float(fg.x & 0xffff0000u);
      float g2 = __uint_as_float(fg.y << 16);
      float g3 = __uint_as_float(fg.y & 0xffff0000u);
      int up = __builtin_amdgcn_update_dpp(
          __float_as_int(NEG2), __float_as_int(a3), 0x138, 0xF, 0xF, false);
      float am1 = __int_as_float(up);
      float n0 = lae2g(a0, am1, g0);
      float n1 = lae2g(a1, a0, g1);
      float n2 = lae2g(a2, a1, g2);
      float n3 = lae2g(a3, a2, g3);
      a0 = n0; a1 = n1; a2 = n2; a3 = n3;
    };
    if (tid >= 64 && tid < 256) stage_tile(gb, 16, TB, tid);
    __syncthreads();
    for (int j = 16; j < 32; ++j) {
      if (tid >= 64 && tid < 256) {
        if (j < 31) stage_tile(gb, j + 1, TB + ((j + 1) & 1) * TSZ, tid);
      } else if (tid < 64) {
        __builtin_amdgcn_s_setprio(1);
        const u16* fs = TB + (j & 1) * TSZ + 4 * l;
        uint2 fb[2][4];
#pragma unroll
        for (int k = 0; k < 4; ++k) fb[0][k] = *(const uint2*)(fs + k * TSTR);
#pragma unroll
        for (int g = 0; g < 8; ++g) {
          const int cur = g & 1, nxt = cur ^ 1;
          if (g < 7) {
#pragma unroll
            for (int k = 0; k < 4; ++k)
              fb[nxt][k] = *(const uint2*)(fs + ((g + 1) * 4 + k) * TSTR);
          }
#pragma unroll
          for (int k = 0; k < 4; ++k) FWD(fb[cur][k]);
        }
        __builtin_amdgcn_s_setprio(0);
      }
      __syncthreads();
    }
    if (tid < 64)
      *(float4*)&ws->A[b * 256 + 4 * l] = make_float4(a0, a1, a2, a3);
    return;
  }

  if (bid < 128) {  // ---- bwd segment 2: tiles kbT-16..kbT-31 ----
    const int b = bid - 64;
    const int T = mel_lens[b] - 1;
    const int kbT = T >> 5;
    float b0 = NEG2, b1 = NEG2, b2 = NEG2, b3 = NEG2;
    if (tid < 64) {
      float4 c = *(const float4*)&ws->ckB[b * 256 + 4 * l];
      b0 = c.x; b1 = c.y; b2 = c.z; b3 = c.w;
    }
    if (kbT - 16 < 32) {  // nothing to do; pass checkpoint through
      if (tid < 64)
        *(float4*)&ws->Bv[b * 256 + 4 * l] = make_float4(b0, b1, b2, b3);
      return;
    }
    const float* gb = logp + (size_t)b * 256 * 2048;
    auto BWD = [&](uint2 bg, bool act) {
      float g0 = __uint_as_float(bg.x << 16);
      float g1 = __uint_as_float(bg.x & 0xffff0000u);
      float g2 = __uint_as_float(bg.y << 16);
      float g3 = __uint_as_float(bg.y & 0xffff0000u);
      float c0 = b0 + g0, c1 = b1 + g1, c2 = b2 + g2, c3 = b3 + g3;
      int dn = __builtin_amdgcn_update_dpp(
          __float_as_int(NEG2), __float_as_int(c0), 0x130, 0xF, 0xF, false);
      float cp = __int_as_float(dn);
      float m0 = lse2f(c0, c1);
      float m1 = lse2f(c1, c2);
      float m2 = lse2f(c2, c3);
      float m3 = lse2f(c3, cp);
      b0 = act ? m0 : b0; b1 = act ? m1 : b1;
      b2 = act ? m2 : b2; b3 = act ? m3 : b3;
    };
    if (tid >= 64 && tid < 256) stage_tile(gb, kbT - 16, TB, tid);
    __syncthreads();
    for (int j = 16; j < 32; ++j) {
      if (tid >= 64 && tid < 256) {
        int bk = kbT - j - 1;
        if (j < 31 && bk >= 32) stage_tile(gb, bk, TB + ((j + 1) & 1) * TSZ, tid);
      } else if (tid < 64) {
        __builtin_amdgcn_s_setprio(1);
        const u16* bs = TB + (j & 1) * TSZ + 4 * l;
        const bool act = (kbT - j) >= 32;
        uint2 bb[2][4];
#pragma unroll
        for (int k = 0; k < 4; ++k) bb[0][k] = *(const uint2*)(bs + (31 - k) * TSTR);
#pragma unroll
        for (int g = 0; g < 8; ++g) {
          const int cur = g & 1, nxt = cur ^ 1;
          if (g < 7) {
#pragma unroll
            for (int k = 0; k < 4; ++k)
              bb[nxt][k] = *(const uint2*)(bs + (31 - ((g + 1) * 4 + k)) * TSTR);
          }
#pragma unroll
          for (int k = 0; k < 4; ++k) BWD(bb[cur][k], act);
        }
        __builtin_amdgcn_s_setprio(0);
      }
      __syncthreads();
    }
    if (tid < 64)
      *(float4*)&ws->Bv[b * 256 + 4 * l] = make_float4(b0, b1, b2, b3);
    return;
  }

  // ---- SSIM conv: odd global tiles ----
  conv_tile((bid - 128) * 2 + 1, deco, dect, mel_lens, ws, SMF, tid);
}

// ------ Kernel 3: combine LSE(A+B) + finalize scalar ------
__global__ __launch_bounds__(256) void kfin(
    const int* __restrict__ mel_lens, const int* __restrict__ inp_lens,
    Ws* __restrict__ ws, float* __restrict__ out) {
  __shared__ float MD[64];
  __shared__ double LD[4][4];
  int tid = threadIdx.x;
  {
    int b = tid >> 2, q = tid & 3;
    const float* Ab = ws->A + b * 256;
    const float* Bb = ws->Bv + b * 256;
    float mx = -3.0e38f;
    for (int j = q; j < 256; j += 4) mx = fmaxf(mx, Ab[j] + Bb[j]);
    mx = fmaxf(mx, __shfl_xor(mx, 1));
    mx = fmaxf(mx, __shfl_xor(mx, 2));
    float se = 0.f;
    for (int j = q; j < 256; j += 4)
      se += __builtin_amdgcn_exp2f(Ab[j] + Bb[j] - mx);
    se += __shfl_xor(se, 1);
    se += __shfl_xor(se, 2);
    if (q == 0)  // deferred per-step eps: + T * 1e-4 (natural log domain)
      MD[b] = LN2 * (mx + __builtin_amdgcn_logf(se)) + (float)(mel_lens[b] - 1) * 1e-4f;
  }
  __syncthreads();
  double sp = 0.0;
  for (int i = tid; i < 64 * NPART; i += 256) sp += ws->spec_part[i];
  double md = 0.0, ml = 0.0, il = 0.0;
  if (tid < 64) {
    md = (double)MD[tid];
    ml = (double)mel_lens[tid];
    il = (double)inp_lens[tid];
  }
  for (int o = 32; o; o >>= 1) {
    sp += __shfl_xor(sp, o);
    md += __shfl_xor(md, o);
    ml += __shfl_xor(ml, o);
    il += __shfl_xor(il, o);
  }
  int w = tid >> 6;
  if ((tid & 63) == 0) { LD[w][0] = sp; LD[w][1] = md; LD[w][2] = ml; LD[w][3] = il; }
  __syncthreads();
  if (tid == 0) {
    sp = LD[0][0] + LD[1][0] + LD[2][0] + LD[3][0];
    md = LD[0][1] + LD[1][1] + LD[2][1] + LD[3][1];
    ml = LD[0][2] + LD[1][2] + LD[2][2] + LD[3][2];
    il = LD[0][3] + LD[1][3] + LD[2][3] + LD[3][3];
    double spec = sp / (ml * 80.0);
    double dur = ws->dur_sum / il;
    double mdn = -(md / 64.0) / 256.0;
    double sm = ws->ssim_sum / (64.0 * 2038.0 * 70.0);
    double sl = 1.0 - sm;
    sl = sl < 0.0 ? 0.0 : (sl > 1.0 ? 1.0 : sl);
    out[0] = (float)(spec + sl + dur + mdn);
  }
}

extern "C" void kernel_launch(void* const* d_in, const int* in_sizes, int n_in,
                              void* d_out, int out_size, void* d_ws, size_t ws_size,
                              hipStream_t stream) {
  const float* logp = (const float*)d_in[0];
  const float* deco = (const float*)d_in[1];
  const float* dect = (const float*)d_in[2];
  const float* duro = (const float*)d_in[3];
  const float* durt = (const float*)d_in[4];
  const int* mel_lens = (const int*)d_in[5];
  const int* inp_lens = (const int*)d_in[6];
  Ws* ws = (Ws*)d_ws;
  hipLaunchKernelGGL(k0, dim3(64 * NPART + 1), dim3(256), 0, stream,
                     deco, dect, duro, durt, mel_lens, inp_lens, ws);
  hipLaunchKernelGGL(kseg1, dim3(128 + 2048), dim3(512), 0, stream,
                     logp, deco, dect, mel_lens, inp_lens, ws);
  hipLaunchKernelGGL(kseg2, dim3(128 + 2048), dim3(512), 0, stream,
                     logp, deco, dect, mel_lens, inp_lens, ws);
  hipLaunchKernelGGL(kfin, dim3(1), dim3(256), 0, stream,
                     mel_lens, inp_lens, ws, (float*)d_out);
}

// Round 22
// 156.946 us; speedup vs baseline: 1.0332x; 1.0332x over previous
//
#include <hip/hip_runtime.h>
#include <math.h>

typedef unsigned short u16;
typedef unsigned int u32;

#define INV_LN2 1.44269504088896f
#define LN2     0.693147180559945f
#define NEG2    (-14426.9504f)          // -10000 * INV_LN2

// Problem dims (fixed): B=64, T_seq=256, T_mel=2048, D=80; SSIM out = 2038 x 70

struct Ws {
  double ssim_sum;
  double dur_sum;
  double spec_part[256];
  float  mnT[256], mxT[256], mnO[256], mxO[256];
  float  A[64 * 256];    // fwd alpha at t=1023 (log2 domain)
  float  Bv[64 * 256];   // bwd beta  at t=1023 (log2 domain)
  float  ckF[64 * 256];  // fwd checkpoint after t=511
  float  ckB[64 * 256];  // bwd checkpoint after tiles kbT..kbT-15
};

__device__ __forceinline__ float lse2f(float a, float b) {
  float m = fmaxf(a, b);
  float d = fabsf(a - b);
  return m + __builtin_amdgcn_logf(1.0f + __builtin_amdgcn_exp2f(-d));
}
__device__ __forceinline__ float lae2g(float a, float b, float g) {
  float m = fmaxf(a, b);
  float d = fabsf(a - b);
  return (m + g) + __builtin_amdgcn_logf(1.0f + __builtin_amdgcn_exp2f(-d));
}
__device__ __forceinline__ u16 bf16rn(float f) {
  u32 u = __float_as_uint(f);
  u32 r = (u + 0x7fffu + ((u >> 16) & 1u)) >> 16;
  return (u16)r;
}

constexpr float G11[11] = {
  0.00102838f, 0.00759876f, 0.03600077f, 0.10936070f, 0.21300554f,
  0.26601172f,
  0.21300554f, 0.10936070f, 0.03600077f, 0.00759876f, 0.00102838f};

#define TSTR 264                 // u16 row stride per t_local
#define TSZ  (32 * TSTR)

// Producers (lanes 64..255): stage tile kb (32 t-steps), transposed
// [t][s] bf16, pre-scaled by 1/ln2.  Identical to round-12 (verified).
__device__ __forceinline__ void stage_tile(const float* __restrict__ gb, int kb,
                                           u16* dst, int tid) {
  const int ltid = tid - 64;
  const int tb = kb << 5;
#pragma unroll
  for (int it = 0; it < 11; ++it) {
    int i = ltid + it * 192;
    if (i < 2048) {
      int s = i >> 3, e = i & 7;
      float4 v = *(const float4*)(gb + (size_t)s * 2048 + tb + 4 * e);
      u16* d = dst + (4 * e) * TSTR + s;
      d[0]        = bf16rn(v.x * INV_LN2);
      d[TSTR]     = bf16rn(v.y * INV_LN2);
      d[2 * TSTR] = bf16rn(v.z * INV_LN2);
      d[3 * TSTR] = bf16rn(v.w * INV_LN2);
    }
  }
}

// ---------------- Kernel 0: minmax + spec MSE partials || dur ----------------
__global__ __launch_bounds__(256) void k0(
    const float* __restrict__ deco, const float* __restrict__ dect,
    const float* __restrict__ duro, const float* __restrict__ durt,
    const int* __restrict__ mel_lens, const int* __restrict__ inp_lens,
    Ws* __restrict__ ws) {
  __shared__ float L[5][4];
  const int bid = blockIdx.x, tid = threadIdx.x;

  if (bid < 256) {  // min/max + spec partial: 4 blocks per batch, 512 rows each
    int idx = bid, b = idx >> 2, part = idx & 3;
    int len = mel_lens[b];
    int rbeg = part * 512;
    int rcnt = len - rbeg; rcnt = rcnt < 0 ? 0 : (rcnt > 512 ? 512 : rcnt);
    float mnT = __builtin_inff(), mxT = -__builtin_inff();
    float mnO = __builtin_inff(), mxO = -__builtin_inff();
    float ssum = 0.f;
    if (rcnt > 0) {
      const float4* po = (const float4*)(deco + ((size_t)(b * 2048 + rbeg)) * 80);
      const float4* pt = (const float4*)(dect + ((size_t)(b * 2048 + rbeg)) * 80);
      int n4 = rcnt * 20;
      for (int i = tid; i < n4; i += 256) {
        float4 vo = po[i], vt = pt[i];
        mnO = fminf(mnO, fminf(fminf(vo.x, vo.y), fminf(vo.z, vo.w)));
        mxO = fmaxf(mxO, fmaxf(fmaxf(vo.x, vo.y), fmaxf(vo.z, vo.w)));
        mnT = fminf(mnT, fminf(fminf(vt.x, vt.y), fminf(vt.z, vt.w)));
        mxT = fmaxf(mxT, fmaxf(fmaxf(vt.x, vt.y), fmaxf(vt.z, vt.w)));
        float dx = vo.x - vt.x, dy = vo.y - vt.y, dz = vo.z - vt.z, dw = vo.w - vt.w;
        ssum += dx * dx + dy * dy + dz * dz + dw * dw;
      }
    }
    for (int o = 32; o; o >>= 1) {
      mnT = fminf(mnT, __shfl_xor(mnT, o));
      mxT = fmaxf(mxT, __shfl_xor(mxT, o));
      mnO = fminf(mnO, __shfl_xor(mnO, o));
      mxO = fmaxf(mxO, __shfl_xor(mxO, o));
      ssum += __shfl_xor(ssum, o);
    }
    int w = tid >> 6;
    if ((tid & 63) == 0) { L[0][w] = mnT; L[1][w] = mxT; L[2][w] = mnO; L[3][w] = mxO; L[4][w] = ssum; }
    __syncthreads();
    if (tid == 0) {
      mnT = fminf(fminf(L[0][0], L[0][1]), fminf(L[0][2], L[0][3]));
      mxT = fmaxf(fmaxf(L[1][0], L[1][1]), fmaxf(L[1][2], L[1][3]));
      mnO = fminf(fminf(L[2][0], L[2][1]), fminf(L[2][2], L[2][3]));
      mxO = fmaxf(fmaxf(L[3][0], L[3][1]), fmaxf(L[3][2], L[3][3]));
      ssum = L[4][0] + L[4][1] + L[4][2] + L[4][3];
      ws->mnT[idx] = mnT; ws->mxT[idx] = mxT; ws->mnO[idx] = mnO; ws->mxO[idx] = mxO;
      ws->spec_part[idx] = (double)ssum;
    }
    return;
  }

  {  // dur MSE + zero ssim accumulator
    float ssum = 0.f;
    for (int i = tid; i < 64 * 256; i += 256) {
      int b2 = i >> 8, s2 = i & 255;
      if (s2 < inp_lens[b2]) { float d = duro[i] - durt[i]; ssum += d * d; }
    }
    for (int o = 32; o; o >>= 1) ssum += __shfl_xor(ssum, o);
    int w = tid >> 6;
    if ((tid & 63) == 0) L[4][w] = ssum;
    __syncthreads();
    if (tid == 0) {
      ws->dur_sum = (double)(L[4][0] + L[4][1] + L[4][2] + L[4][3]);
      ws->ssim_sum = 0.0;
    }
  }
}

// Shared SSIM conv tile body (r18-verified form), 512 threads.
__device__ __forceinline__ void conv_tile(
    int gci, const float* __restrict__ deco, const float* __restrict__ dect,
    const int* __restrict__ mel_lens, Ws* __restrict__ ws, float* SMF, int tid) {
  float* cc = SMF;
  float* R = SMF + 14700;  // [8]
  int b = gci >> 6, tile = gci & 63;
  int r0 = tile * 32;
  int nrows = 2038 - r0; nrows = nrows > 32 ? 32 : nrows;
  int nin = nrows + 10;
  int len = mel_lens[b];

  // EXACT shortcut: tiles fully past the mask -> ssim_map == 1.0 exactly.
  if (r0 >= len) {
    if (tid == 0) atomicAdd(&ws->ssim_sum, (double)(nrows * 70));
    return;
  }

  float mnT = fminf(fminf(ws->mnT[4 * b], ws->mnT[4 * b + 1]), fminf(ws->mnT[4 * b + 2], ws->mnT[4 * b + 3]));
  float mxT = fmaxf(fmaxf(ws->mxT[4 * b], ws->mxT[4 * b + 1]), fmaxf(ws->mxT[4 * b + 2], ws->mxT[4 * b + 3]));
  float mnO = fminf(fminf(ws->mnO[4 * b], ws->mnO[4 * b + 1]), fminf(ws->mnO[4 * b + 2], ws->mnO[4 * b + 3]));
  float mxO = fmaxf(fmaxf(ws->mxO[4 * b], ws->mxO[4 * b + 1]), fmaxf(ws->mxO[4 * b + 2], ws->mxO[4 * b + 3]));
  if (len < 2048) { mxT = fmaxf(mxT, 0.f); mxO = fmaxf(mxO, 0.f); }
  float sT = 1.0f / (mxT - mnT + 1e-8f);
  float sO = 1.0f / (mxO - mnO + 1e-8f);
  const float* po = deco + (size_t)b * 2048 * 80;
  const float* pt = dect + (size_t)b * 2048 * 80;

  // Phase A: column conv (80 -> 70), float4-vectorized quad-j tasks.
  for (int task = tid; task < nin * 18; task += 512) {
    int r = task / 18, q = task - 18 * r;
    int j0 = q * 4;
    int grow = r0 + r;
    float sacc[4][5];
#pragma unroll
    for (int e = 0; e < 4; ++e)
#pragma unroll
      for (int c = 0; c < 5; ++c) sacc[e][c] = 0.f;
    if (grow < len) {
      const float* rowt = pt + (size_t)grow * 80 + j0;
      const float* rowo = po + (size_t)grow * 80 + j0;
      float ft[16], fo[16];
      *(float4*)&ft[0]  = *(const float4*)(rowt);
      *(float4*)&ft[4]  = *(const float4*)(rowt + 4);
      *(float4*)&ft[8]  = *(const float4*)(rowt + 8);
      *(float4*)&ft[12] = (j0 == 68) ? *(const float4*)(rowt + 8)
                                     : *(const float4*)(rowt + 12);
      *(float4*)&fo[0]  = *(const float4*)(rowo);
      *(float4*)&fo[4]  = *(const float4*)(rowo + 4);
      *(float4*)&fo[8]  = *(const float4*)(rowo + 8);
      *(float4*)&fo[12] = (j0 == 68) ? *(const float4*)(rowo + 8)
                                     : *(const float4*)(rowo + 12);
#pragma unroll
      for (int i = 0; i < 16; ++i) {
        ft[i] = (ft[i] - mnT) * sT;
        fo[i] = (fo[i] - mnO) * sO;
      }
#pragma unroll
      for (int e = 0; e < 4; ++e) {
#pragma unroll
        for (int k = 0; k < 11; ++k) {
          float tn = ft[e + k], on = fo[e + k], g = G11[k];
          sacc[e][0] = fmaf(g, tn, sacc[e][0]);
          sacc[e][1] = fmaf(g, on, sacc[e][1]);
          sacc[e][2] = fmaf(g * tn, tn, sacc[e][2]);
          sacc[e][3] = fmaf(g * on, on, sacc[e][3]);
          sacc[e][4] = fmaf(g * on, tn, sacc[e][4]);  // g*tn*on (order-equal)
        }
      }
    }
    int base = r * 70 + j0;
#pragma unroll
    for (int c = 0; c < 5; ++c) {
      *(float2*)&cc[c * 2940 + base] = make_float2(sacc[0][c], sacc[1][c]);
      if (j0 < 68)
        *(float2*)&cc[c * 2940 + base + 2] = make_float2(sacc[2][c], sacc[3][c]);
    }
  }
  __syncthreads();

  // Phase B: row conv + SSIM formula (verified simple form)
  float acc = 0.f;
  for (int q2 = tid; q2 < nrows * 70; q2 += 512) {
    int i = q2 / 70, j = q2 - 70 * i;
    float mx = 0, my = 0, xx = 0, yy = 0, xy = 0;
#pragma unroll
    for (int k = 0; k < 11; ++k) {
      float g = G11[k];
      int o = (i + k) * 70 + j;
      mx = fmaf(g, cc[o], mx);
      my = fmaf(g, cc[2940 + o], my);
      xx = fmaf(g, cc[2 * 2940 + o], xx);
      yy = fmaf(g, cc[3 * 2940 + o], yy);
      xy = fmaf(g, cc[4 * 2940 + o], xy);
    }
    float vx = xx - mx * mx, vy = yy - my * my, vxy = xy - mx * my;
    float cs = (2.f * vxy + 9e-4f) / (vx + vy + 9e-4f);
    float lum = (2.f * mx * my + 1e-4f) / (mx * mx + my * my + 1e-4f);
    acc += lum * cs;
  }
  for (int o = 32; o; o >>= 1) acc += __shfl_xor(acc, o);
  if ((tid & 63) == 0) R[tid >> 6] = acc;
  __syncthreads();
  if (tid == 0)
    atomicAdd(&ws->ssim_sum,
              (double)(R[0] + R[1] + R[2] + R[3] + R[4] + R[5] + R[6] + R[7]));
}

// ------- Kernel 1 (512 threads): fwd seg1 || bwd seg1 || conv (even tiles) -------
__global__ __launch_bounds__(512) void kseg1(
    const float* __restrict__ logp,
    const float* __restrict__ deco, const float* __restrict__ dect,
    const int* __restrict__ mel_lens, const int* __restrict__ inp_lens,
    Ws* __restrict__ ws) {
  __shared__ float SMF[14712];   // 58848 B; MDN aliases first 33792 B
  const int bid = blockIdx.x, tid = threadIdx.x;
  const int l = tid;
  u16* TB = (u16*)SMF;

  if (bid < 64) {  // ---- fwd segment 1: tiles 0..15 (t = 1..511) ----
    const int b = bid;
    const float* gb = logp + (size_t)b * 256 * 2048;
    float a0 = NEG2, a1 = NEG2, a2 = NEG2, a3 = NEG2;
    if (tid < 64 && l == 0) a0 = gb[0] * INV_LN2;
    auto FWD = [&](uint2 fg) {
      float g0 = __uint_as_float(fg.x << 16);
      float g1 = __uint_as_float(fg.x & 0xffff0000u);
      float g2 = __uint_as_float(fg.y << 16);
      float g3 = __uint_as_float(fg.y & 0xffff0000u);
      int up = __builtin_amdgcn_update_dpp(
          __float_as_int(NEG2), __float_as_int(a3), 0x138, 0xF, 0xF, false);
      float am1 = __int_as_float(up);
      float n0 = lae2g(a0, am1, g0);
      float n1 = lae2g(a1, a0, g1);
      float n2 = lae2g(a2, a1, g2);
      float n3 = lae2g(a3, a2, g3);
      a0 = n0; a1 = n1; a2 = n2; a3 = n3;
    };
    if (tid >= 64 && tid < 256) stage_tile(gb, 0, TB, tid);
    __syncthreads();
    // j = 0 peel (skip t=0)
    if (tid >= 64 && tid < 256) stage_tile(gb, 1, TB + TSZ, tid);
    else if (tid < 64) {
      const u16* fs = TB + 4 * l;
      for (int i = 1; i < 32; ++i) FWD(*(const uint2*)(fs + i * TSTR));
    }
    __syncthreads();
    for (int j = 1; j < 16; ++j) {
      if (tid >= 64 && tid < 256) {
        if (j < 15) stage_tile(gb, j + 1, TB + ((j + 1) & 1) * TSZ, tid);
      } else if (tid < 64) {
        __builtin_amdgcn_s_setprio(1);
        const u16* fs = TB + (j & 1) * TSZ + 4 * l;
        uint2 fb[2][4];
#pragma unroll
        for (int k = 0; k < 4; ++k) fb[0][k] = *(const uint2*)(fs + k * TSTR);
#pragma unroll
        for (int g = 0; g < 8; ++g) {
          const int cur = g & 1, nxt = cur ^ 1;
          if (g < 7) {
#pragma unroll
            for (int k = 0; k < 4; ++k)
              fb[nxt][k] = *(const uint2*)(fs + ((g + 1) * 4 + k) * TSTR);
          }
#pragma unroll
          for (int k = 0; k < 4; ++k) FWD(fb[cur][k]);
        }
        __builtin_amdgcn_s_setprio(0);
      }
      __syncthreads();
    }
    if (tid < 64)
      *(float4*)&ws->ckF[b * 256 + 4 * l] = make_float4(a0, a1, a2, a3);
    return;
  }

  if (bid < 128) {  // ---- bwd segment 1: tiles kbT..kbT-15 ----
    const int b = bid - 64;
    const int T = mel_lens[b] - 1;
    const int ss = inp_lens[b] - 1;
    const int kbT = T >> 5;
    const float* gb = logp + (size_t)b * 256 * 2048;
    float b0 = NEG2, b1 = NEG2, b2 = NEG2, b3 = NEG2;
    if (tid < 64) {
      b0 = (4 * l + 0 == ss) ? 0.f : NEG2;
      b1 = (4 * l + 1 == ss) ? 0.f : NEG2;
      b2 = (4 * l + 2 == ss) ? 0.f : NEG2;
      b3 = (4 * l + 3 == ss) ? 0.f : NEG2;
    }
    auto BWD = [&](uint2 bg, bool act) {
      float g0 = __uint_as_float(bg.x << 16);
      float g1 = __uint_as_float(bg.x & 0xffff0000u);
      float g2 = __uint_as_float(bg.y << 16);
      float g3 = __uint_as_float(bg.y & 0xffff0000u);
      float c0 = b0 + g0, c1 = b1 + g1, c2 = b2 + g2, c3 = b3 + g3;
      int dn = __builtin_amdgcn_update_dpp(
          __float_as_int(NEG2), __float_as_int(c0), 0x130, 0xF, 0xF, false);
      float cp = __int_as_float(dn);
      float m0 = lse2f(c0, c1);
      float m1 = lse2f(c1, c2);
      float m2 = lse2f(c2, c3);
      float m3 = lse2f(c3, cp);
      b0 = act ? m0 : b0; b1 = act ? m1 : b1;
      b2 = act ? m2 : b2; b3 = act ? m3 : b3;
    };
    if (tid >= 64 && tid < 256) { if (kbT >= 32) stage_tile(gb, kbT, TB, tid); }
    __syncthreads();
    // j = 0 peel (per-t guard tt <= T)
    if (tid >= 64 && tid < 256) {
      if (kbT - 1 >= 32) stage_tile(gb, kbT - 1, TB + TSZ, tid);
    } else if (tid < 64 && kbT >= 32) {
      const u16* bs = TB + 4 * l;
      for (int ii = 31; ii >= 0; --ii) {
        int tt = (kbT << 5) + ii;
        if (tt <= T) BWD(*(const uint2*)(bs + ii * TSTR), true);
      }
    }
    __syncthreads();
    for (int j = 1; j < 16; ++j) {
      if (tid >= 64 && tid < 256) {
        int bk = kbT - j - 1;
        if (j < 15 && bk >= 32) stage_tile(gb, bk, TB + ((j + 1) & 1) * TSZ, tid);
      } else if (tid < 64) {
        __builtin_amdgcn_s_setprio(1);
        const u16* bs = TB + (j & 1) * TSZ + 4 * l;
        const bool act = (kbT - j) >= 32;
        uint2 bb[2][4];
#pragma unroll
        for (int k = 0; k < 4; ++k) bb[0][k] = *(const uint2*)(bs + (31 - k) * TSTR);
#pragma unroll
        for (int g = 0; g < 8; ++g) {
          const int cur = g & 1, nxt = cur ^ 1;
          if (g < 7) {
#pragma unroll
            for (int k = 0; k < 4; ++k)
              bb[nxt][k] = *(const uint2*)(bs + (31 - ((g + 1) * 4 + k)) * TSTR);
          }
#pragma unroll
          for (int k = 0; k < 4; ++k) BWD(bb[cur][k], act);
        }
        __builtin_amdgcn_s_setprio(0);
      }
      __syncthreads();
    }
    if (tid < 64)
      *(float4*)&ws->ckB[b * 256 + 4 * l] = make_float4(b0, b1, b2, b3);
    return;
  }

  // ---- SSIM conv: even global tiles ----
  conv_tile((bid - 128) * 2, deco, dect, mel_lens, ws, SMF, tid);
}

// ------- Kernel 2 (512 threads): fwd seg2 || bwd seg2 || conv (odd tiles) -------
__global__ __launch_bounds__(512) void kseg2(
    const float* __restrict__ logp,
    const float* __restrict__ deco, const float* __restrict__ dect,
    const int* __restrict__ mel_lens, const int* __restrict__ inp_lens,
    Ws* __restrict__ ws) {
  __shared__ float SMF[14712];
  const int bid = blockIdx.x, tid = threadIdx.x;
  const int l = tid;
  u16* TB = (u16*)SMF;

  if (bid < 64) {  // ---- fwd segment 2: tiles 16..31 (t = 512..1023) ----
    const int b = bid;
    const float* gb = logp + (size_t)b * 256 * 2048;
    float a0 = NEG2, a1 = NEG2, a2 = NEG2, a3 = NEG2;
    if (tid < 64) {
      float4 c = *(const float4*)&ws->ckF[b * 256 + 4 * l];
      a0 = c.x; a1 = c.y; a2 = c.z; a3 = c.w;
    }
    auto FWD = [&](uint2 fg) {
      float g0 = __uint_as_float(fg.x << 16);
      float g1 = __uint_as_float(fg.x & 0xffff0000u);
      float g2 = __uint_as_float(fg.y << 16);
      float g3 = __uint_as_float(fg.y & 0xffff0000u);
      int up = __builtin_amdgcn_update_dpp(
          __float_as_int(NEG2), __float_as_int(a3), 0x138, 0xF, 0xF, false);
      float am1 = __int_as_float(up);
      float n0 = lae2g(a0, am1, g0);
      float n1 = lae2g(a1, a0, g1);
      float n2 = lae2g(a2, a1, g2);
      float n3 = lae2g(a3, a2, g3);
      a0 = n0; a1 = n1; a2 = n2; a3 = n3;
    };
    if (tid >= 64 && tid < 256) stage_tile(gb, 16, TB, tid);
    __syncthreads();
    for (int j = 16; j < 32; ++j) {
      if (tid >= 64 && tid < 256) {
        if (j < 31) stage_tile(gb, j + 1, TB + ((j + 1) & 1) * TSZ, tid);
      } else if (tid < 64) {
        __builtin_amdgcn_s_setprio(1);
        const u16* fs = TB + (j & 1) * TSZ + 4 * l;
        uint2 fb[2][4];
#pragma unroll
        for (int k = 0; k < 4; ++k) fb[0][k] = *(const uint2*)(fs + k * TSTR);
#pragma unroll
        for (int g = 0; g < 8; ++g) {
          const int cur = g & 1, nxt = cur ^ 1;
          if (g < 7) {
#pragma unroll
            for (int k = 0; k < 4; ++k)
              fb[nxt][k] = *(const uint2*)(fs + ((g + 1) * 4 + k) * TSTR);
          }
#pragma unroll
          for (int k = 0; k < 4; ++k) FWD(fb[cur][k]);
        }
        __builtin_amdgcn_s_setprio(0);
      }
      __syncthreads();
    }
    if (tid < 64)
      *(float4*)&ws->A[b * 256 + 4 * l] = make_float4(a0, a1, a2, a3);
    return;
  }

  if (bid < 128) {  // ---- bwd segment 2: tiles kbT-16..kbT-31 ----
    const int b = bid - 64;
    const int T = mel_lens[b] - 1;
    const int kbT = T >> 5;
    float b0 = NEG2, b1 = NEG2, b2 = NEG2, b3 = NEG2;
    if (tid < 64) {
      float4 c = *(const float4*)&ws->ckB[b * 256 + 4 * l];
      b0 = c.x; b1 = c.y; b2 = c.z; b3 = c.w;
    }
    if (kbT - 16 < 32) {  // nothing to do; pass checkpoint through
      if (tid < 64)
        *(float4*)&ws->Bv[b * 256 + 4 * l] = make_float4(b0, b1, b2, b3);
      return;
    }
    const float* gb = logp + (size_t)b * 256 * 2048;
    auto BWD = [&](uint2 bg, bool act) {
      float g0 = __uint_as_float(bg.x << 16);
      float g1 = __uint_as_float(bg.x & 0xffff0000u);
      float g2 = __uint_as_float(bg.y << 16);
      float g3 = __uint_as_float(bg.y & 0xffff0000u);
      float c0 = b0 + g0, c1 = b1 + g1, c2 = b2 + g2, c3 = b3 + g3;
      int dn = __builtin_amdgcn_update_dpp(
          __float_as_int(NEG2), __float_as_int(c0), 0x130, 0xF, 0xF, false);
      float cp = __int_as_float(dn);
      float m0 = lse2f(c0, c1);
      float m1 = lse2f(c1, c2);
      float m2 = lse2f(c2, c3);
      float m3 = lse2f(c3, cp);
      b0 = act ? m0 : b0; b1 = act ? m1 : b1;
      b2 = act ? m2 : b2; b3 = act ? m3 : b3;
    };
    if (tid >= 64 && tid < 256) stage_tile(gb, kbT - 16, TB, tid);
    __syncthreads();
    for (int j = 16; j < 32; ++j) {
      if (tid >= 64 && tid < 256) {
        int bk = kbT - j - 1;
        if (j < 31 && bk >= 32) stage_tile(gb, bk, TB + ((j + 1) & 1) * TSZ, tid);
      } else if (tid < 64) {
        __builtin_amdgcn_s_setprio(1);
        const u16* bs = TB + (j & 1) * TSZ + 4 * l;
        const bool act = (kbT - j) >= 32;
        uint2 bb[2][4];
#pragma unroll
        for (int k = 0; k < 4; ++k) bb[0][k] = *(const uint2*)(bs + (31 - k) * TSTR);
#pragma unroll
        for (int g = 0; g < 8; ++g) {
          const int cur = g & 1, nxt = cur ^ 1;
          if (g < 7) {
#pragma unroll
            for (int k = 0; k < 4; ++k)
              bb[nxt][k] = *(const uint2*)(bs + (31 - ((g + 1) * 4 + k)) * TSTR);
          }
#pragma unroll
          for (int k = 0; k < 4; ++k) BWD(bb[cur][k], act);
        }
        __builtin_amdgcn_s_setprio(0);
      }
      __syncthreads();
    }
    if (tid < 64)
      *(float4*)&ws->Bv[b * 256 + 4 * l] = make_float4(b0, b1, b2, b3);
    return;
  }

  // ---- SSIM conv: odd global tiles ----
  conv_tile((bid - 128) * 2 + 1, deco, dect, mel_lens, ws, SMF, tid);
}

// ------ Kernel 3: combine LSE(A+B) + finalize scalar ------
__global__ __launch_bounds__(256) void kfin(
    const int* __restrict__ mel_lens, const int* __restrict__ inp_lens,
    Ws* __restrict__ ws, float* __restrict__ out) {
  __shared__ float MD[64];
  __shared__ double LD[4][4];
  int tid = threadIdx.x;
  {
    int b = tid >> 2, q = tid & 3;
    const float* Ab = ws->A + b * 256;
    const float* Bb = ws->Bv + b * 256;
    float mx = -3.0e38f;
    for (int j = q; j < 256; j += 4) mx = fmaxf(mx, Ab[j] + Bb[j]);
    mx = fmaxf(mx, __shfl_xor(mx, 1));
    mx = fmaxf(mx, __shfl_xor(mx, 2));
    float se = 0.f;
    for (int j = q; j < 256; j += 4)
      se += __builtin_amdgcn_exp2f(Ab[j] + Bb[j] - mx);
    se += __shfl_xor(se, 1);
    se += __shfl_xor(se, 2);
    if (q == 0)  // deferred per-step eps: + T * 1e-4 (natural log domain)
      MD[b] = LN2 * (mx + __builtin_amdgcn_logf(se)) + (float)(mel_lens[b] - 1) * 1e-4f;
  }
  __syncthreads();
  double sp = ws->spec_part[tid];
  double md = 0.0, ml = 0.0, il = 0.0;
  if (tid < 64) {
    md = (double)MD[tid];
    ml = (double)mel_lens[tid];
    il = (double)inp_lens[tid];
  }
  for (int o = 32; o; o >>= 1) {
    sp += __shfl_xor(sp, o);
    md += __shfl_xor(md, o);
    ml += __shfl_xor(ml, o);
    il += __shfl_xor(il, o);
  }
  int w = tid >> 6;
  if ((tid & 63) == 0) { LD[w][0] = sp; LD[w][1] = md; LD[w][2] = ml; LD[w][3] = il; }
  __syncthreads();
  if (tid == 0) {
    sp = LD[0][0] + LD[1][0] + LD[2][0] + LD[3][0];
    md = LD[0][1] + LD[1][1] + LD[2][1] + LD[3][1];
    ml = LD[0][2] + LD[1][2] + LD[2][2] + LD[3][2];
    il = LD[0][3] + LD[1][3] + LD[2][3] + LD[3][3];
    double spec = sp / (ml * 80.0);
    double dur = ws->dur_sum / il;
    double mdn = -(md / 64.0) / 256.0;
    double sm = ws->ssim_sum / (64.0 * 2038.0 * 70.0);
    double sl = 1.0 - sm;
    sl = sl < 0.0 ? 0.0 : (sl > 1.0 ? 1.0 : sl);
    out[0] = (float)(spec + sl + dur + mdn);
  }
}

extern "C" void kernel_launch(void* const* d_in, const int* in_sizes, int n_in,
                              void* d_out, int out_size, void* d_ws, size_t ws_size,
                              hipStream_t stream) {
  const float* logp = (const float*)d_in[0];
  const float* deco = (const float*)d_in[1];
  const float* dect = (const float*)d_in[2];
  const float* duro = (const float*)d_in[3];
  const float* durt = (const float*)d_in[4];
  const int* mel_lens = (const int*)d_in[5];
  const int* inp_lens = (const int*)d_in[6];
  Ws* ws = (Ws*)d_ws;
  hipLaunchKernelGGL(k0, dim3(257), dim3(256), 0, stream,
                     deco, dect, duro, durt, mel_lens, inp_lens, ws);
  hipLaunchKernelGGL(kseg1, dim3(128 + 2048), dim3(512), 0, stream,
                     logp, deco, dect, mel_lens, inp_lens, ws);
  hipLaunchKernelGGL(kseg2, dim3(128 + 2048), dim3(512), 0, stream,
                     logp, deco, dect, mel_lens, inp_lens, ws);
  hipLaunchKernelGGL(kfin, dim3(1), dim3(256), 0, stream,
                     mel_lens, inp_lens, ws, (float*)d_out);
}